// Round 14
// baseline (129.658 us; speedup 1.0000x reference)
//
#include <hip/hip_runtime.h>
#include <hip/hip_bf16.h>
#include <hip/hip_fp16.h>
#include <math.h>

#define B_  2
#define NQ  13294
#define NK  13294
#define M_  (B_ * NK)   // 26588
#define MT  32
#define GX  ((M_ + MT - 1) / MT)  // 831

typedef __bf16 bf16x8 __attribute__((ext_vector_type(8)));
typedef float f32x4 __attribute__((ext_vector_type(4)));

static __device__ __forceinline__ f32x4 mfma16(bf16x8 a, bf16x8 b, f32x4 c) {
  return __builtin_amdgcn_mfma_f32_16x16x32_bf16(a, b, c, 0, 0, 0);
}

// ---- pack weights f32 [K=256][N] -> bf16 MFMA B-fragment layout ----
static __device__ __forceinline__ void pack_one(
    const float* __restrict__ W1, const float* __restrict__ W2,
    int N1, int Ntot, __hip_bfloat16* __restrict__ out, int g) {
  int lane = g & 63;
  int n_sub = (g >> 6) & 3;
  int kt = (g >> 8) & 7;
  int bn = g >> 11;
  int n = bn * 64 + n_sub * 16 + (lane & 15);
  int k0 = kt * 32 + (lane >> 4) * 8;
  const float* src; int nn, Ns;
  if (n < N1) { src = W1; nn = n; Ns = N1; }
  else        { src = W2; nn = n - N1; Ns = Ntot - N1; }
  bf16x8 v;
#pragma unroll
  for (int j = 0; j < 8; ++j) v[j] = (__bf16)src[(size_t)(k0 + j) * Ns + nn];
  *(bf16x8*)(out + (size_t)g * 8) = v;
}

__global__ __launch_bounds__(256) void pack_all(
    const float* __restrict__ Wv, const float* __restrict__ Ws,
    const float* __restrict__ Wa, const float* __restrict__ Wo,
    __hip_bfloat16* __restrict__ wv_p, __hip_bfloat16* __restrict__ wsa_p,
    __hip_bfloat16* __restrict__ wo_p) {
  const int b = blockIdx.x, t = threadIdx.x;
  if (b < 32)       pack_one(Wv, Wv, 256, 256, wv_p,  b * 256 + t);
  else if (b < 80)  pack_one(Ws, Wa, 256, 384, wsa_p, (b - 32) * 256 + t);
  else              pack_one(Wo, Wo, 256, 256, wo_p,  (b - 80) * 256 + t);
}

// ---- query locality sort: bin by level-0 reference point (32x32 per batch) ----
static __device__ __forceinline__ int bin_of(const float* refp, int b, int q) {
  const size_t base = (((size_t)b * NQ + q) * 4) * 2;  // level 0
  float rx = refp[base + 0], ry = refp[base + 1];
  int bx = (int)(rx * 32.f); bx = bx < 0 ? 0 : (bx > 31 ? 31 : bx);
  int by = (int)(ry * 32.f); by = by < 0 ? 0 : (by > 31 ? 31 : by);
  return b * 1024 + by * 32 + bx;
}

__global__ __launch_bounds__(256) void hist_k(
    const float* __restrict__ refp, unsigned int* __restrict__ hist) {
  int i = blockIdx.x * 256 + threadIdx.x;
  if (i >= 2 * NQ) return;
  int b = i >= NQ; int q = i - b * NQ;
  atomicAdd(&hist[bin_of(refp, b, q)], 1u);
}

__global__ __launch_bounds__(256) void scan_k(
    const unsigned int* __restrict__ hist, unsigned int* __restrict__ cursor) {
  __shared__ unsigned int lds[256];
  const int t = threadIdx.x;
  unsigned int v[8], s = 0;
#pragma unroll
  for (int j = 0; j < 8; ++j) { v[j] = hist[t * 8 + j]; s += v[j]; }
  lds[t] = s; __syncthreads();
  for (int off = 1; off < 256; off <<= 1) {
    unsigned int x = (t >= off) ? lds[t - off] : 0u;
    __syncthreads();
    lds[t] += x;
    __syncthreads();
  }
  unsigned int base = lds[t] - s;
#pragma unroll
  for (int j = 0; j < 8; ++j) { cursor[t * 8 + j] = base; base += v[j]; }
}

__global__ __launch_bounds__(256) void scatter_k(
    const float* __restrict__ refp, unsigned int* __restrict__ cursor,
    unsigned int* __restrict__ perm) {
  int i = blockIdx.x * 256 + threadIdx.x;
  if (i >= 2 * NQ) return;
  int b = i >= NQ; int q = i - b * NQ;
  unsigned int pos = atomicAdd(&cursor[bin_of(refp, b, q)], 1u);
  perm[pos] = (unsigned int)q;
}

// ---- 32-row-tile GEMM (modes 0/1) ----
#define CSTR 68

__global__ __launch_bounds__(128) void gemm_mt(
    const float* __restrict__ inpf, const float* __restrict__ query,
    const bf16x8* __restrict__ wv_p, const bf16x8* __restrict__ wsa_p,
    const float* __restrict__ bv, const float* __restrict__ bs,
    const float* __restrict__ ba,
    __hip_bfloat16* __restrict__ value, __half* __restrict__ params) {
  __shared__ bf16x8 As[8 * 2 * 64];        // 16 KB
  __shared__ float  Cs[2 * MT * CSTR];     // 17.4 KB

  const int t = threadIdx.x;
  const int bm = blockIdx.x * MT;
  const int lane = t & 63, wid = t >> 6;
  const int mode = blockIdx.y;

  {
    const int r = t >> 2;
    const int row = bm + r;
    const int sm = r >> 4;
    const int lb = r & 15;
    const bool ok = row < M_;
    const float* Af = (mode == 0) ? inpf : query;
    const float* ap = Af + (size_t)row * 256 + (t & 3) * 64;
#pragma unroll
    for (int gi = 0; gi < 8; ++gi) {
      float4 u = make_float4(0.f,0.f,0.f,0.f), v = make_float4(0.f,0.f,0.f,0.f);
      if (ok) { u = *(const float4*)(ap + gi * 8); v = *(const float4*)(ap + gi * 8 + 4); }
      bf16x8 w;
      w[0]=(__bf16)u.x; w[1]=(__bf16)u.y; w[2]=(__bf16)u.z; w[3]=(__bf16)u.w;
      w[4]=(__bf16)v.x; w[5]=(__bf16)v.y; w[6]=(__bf16)v.z; w[7]=(__bf16)v.w;
      int k8 = (t & 3) * 8 + gi;
      As[((k8 >> 2) * 2 + sm) * 64 + lb + ((k8 & 3) << 4)] = w;
    }
  }
  __syncthreads();

  const bf16x8* Bp = (mode == 0) ? wv_p : wsa_p;
  const int NB = (mode == 1) ? 6 : 4;
  float* Cw = &Cs[wid * MT * CSTR];

  for (int nb = wid; nb < NB; nb += 2) {
    const int colbase = nb * 64;
    const bf16x8* bpn = Bp + (size_t)nb * 2048;

    f32x4 acc[2][4] = {};
#pragma unroll
    for (int kt = 0; kt < 8; ++kt) {
      bf16x8 a0 = As[(kt * 2 + 0) * 64 + lane];
      bf16x8 a1 = As[(kt * 2 + 1) * 64 + lane];
#pragma unroll
      for (int n = 0; n < 4; ++n) {
        bf16x8 b = bpn[(kt * 4 + n) * 64 + lane];
        acc[0][n] = mfma16(a0, b, acc[0][n]);
        acc[1][n] = mfma16(a1, b, acc[1][n]);
      }
    }

#pragma unroll
    for (int m = 0; m < 2; ++m)
#pragma unroll
      for (int n = 0; n < 4; ++n)
#pragma unroll
        for (int rg = 0; rg < 4; ++rg)
          Cw[(m * 16 + (lane >> 4) * 4 + rg) * CSTR + n * 16 + (lane & 15)] = acc[m][n][rg];

    if (mode == 0) {
#pragma unroll
      for (int p = 0; p < 4; ++p) {
        const int r = (lane >> 3) + p * 8;
        const int c = (lane & 7) * 8;
        const int row = bm + r;
        float4 u = *(float4*)&Cw[r * CSTR + c];
        float4 v = *(float4*)&Cw[r * CSTR + c + 4];
        const float* bias = bv + colbase + c;
        bf16x8 o;
        o[0]=(__bf16)(u.x+bias[0]); o[1]=(__bf16)(u.y+bias[1]);
        o[2]=(__bf16)(u.z+bias[2]); o[3]=(__bf16)(u.w+bias[3]);
        o[4]=(__bf16)(v.x+bias[4]); o[5]=(__bf16)(v.y+bias[5]);
        o[6]=(__bf16)(v.z+bias[6]); o[7]=(__bf16)(v.w+bias[7]);
        if (row < M_)
          *(bf16x8*)(value + (size_t)row * 256 + colbase + c) = o;
      }
    } else {
#pragma unroll
      for (int p = 0; p < 8; ++p) {
        const int r = (lane >> 4) + p * 4;
        const int c = (lane & 15) * 4;
        const int row = bm + r;
        const int col = colbase + c;
        float4 u = *(float4*)&Cw[r * CSTR + c];
        const float* bias = (col < 256) ? (bs + col) : (ba + col - 256);
        u.x += bias[0]; u.y += bias[1]; u.z += bias[2]; u.w += bias[3];
        if (row < M_) {
          __half2 h0 = __floats2half2_rn(u.x, u.y);
          __half2 h1 = __floats2half2_rn(u.z, u.w);
          uint2 st;
          st.x = *(unsigned int*)&h0;
          st.y = *(unsigned int*)&h1;
          *(uint2*)(params + (size_t)row * 384 + col) = st;
        }
      }
    }
  }
}

// ---- fused sampler: 512 threads, 16 queries, pair-entry combo ----
// combo region per (q,h): 32 pair-entries {w2(2xbf16), idx}, CS=66 u32 (8B
// aligned). Gather: x-adjacent corner pair via base + offset:512. Dead-slot
// acc stash -> MFMA out-projection. 33.8 KB LDS.
// __launch_bounds__(512, 6): VGPR cap ~85 (6 waves/SIMD = 75% occupancy);
// (512,8) capped at 64 and SPILLED (R13: VGPR=28, WRITE_SIZE 3x = scratch).
#define CS 66

__global__ __launch_bounds__(512, 6) void sampler(
    const float* __restrict__ refp, const __half* __restrict__ params,
    const __hip_bfloat16* __restrict__ value, const bf16x8* __restrict__ wo_p,
    const float* __restrict__ bo, const unsigned int* __restrict__ perm,
    float* __restrict__ outp) {
  __shared__ unsigned int combo[128 * CS];  // 33.8 KB
  __shared__ unsigned int qmap[16];

  const int c  = blockIdx.x & 7;
  const int kk = blockIdx.x >> 3;
  const int bb = c >> 2;
  const int qb = (c & 3) * 208 + kk;  // 0..831
  const int q0 = qb * 16;

  const int t = threadIdx.x;
  if (t < 16)
    qmap[t] = (q0 + t < NQ) ? perm[(size_t)bb * NQ + q0 + t] : 0xFFFFFFFFu;
  __syncthreads();

  // ---- build: one thread per (q, head, level): 16*8*4 = 512 ----
  {
    const int cqi = t >> 5;
    const int chh = (t >> 2) & 7;
    const int cl  = t & 3;
    const float DIMF[4]  = {100.f, 50.f, 25.f, 13.f};
    const int   LSTART[4] = {0, 10000, 12500, 13125};
    const float dimf  = DIMF[cl];
    const int   Wd    = (int)dimf;
    const int   lbase = LSTART[cl];

    const unsigned int qreal = qmap[cqi];
    const bool valid = qreal != 0xFFFFFFFFu;
    const size_t row = (size_t)bb * NQ + (valid ? qreal : 0);
    const __half* pr = params + row * 384;

    union { uint4 u[2]; __half h[16]; } LG;
    LG.u[0] = *(const uint4*)(pr + 256 + chh * 16);
    LG.u[1] = *(const uint4*)(pr + 256 + chh * 16 + 8);
    float lgf[16];
#pragma unroll
    for (int j = 0; j < 16; ++j) lgf[j] = __half2float(LG.h[j]);
    float m = lgf[0];
#pragma unroll
    for (int j = 1; j < 16; ++j) m = fmaxf(m, lgf[j]);
    float s = 0.f;
#pragma unroll
    for (int j = 0; j < 16; ++j) s += __expf(lgf[j] - m);
    const float inv = valid ? 1.f / s : 0.f;

    const float rx = refp[(row * 4 + cl) * 2 + 0];
    const float ry = refp[(row * 4 + cl) * 2 + 1];
    union { uint4 u; __half h[8]; } OF;
    OF.u = *(const uint4*)(pr + chh * 32 + cl * 8);
    unsigned int* cb = &combo[(cqi * 8 + chh) * CS + cl * 16];

#pragma unroll
    for (int p = 0; p < 4; ++p) {
      const float wa = __expf(lgf[cl * 4 + p] - m) * inv;
      const float x = rx * dimf + __half2float(OF.h[p * 2 + 0]) - 0.5f;
      const float y = ry * dimf + __half2float(OF.h[p * 2 + 1]) - 0.5f;
      const float xf = floorf(x), yf = floorf(y);
      const float dx = x - xf, dy = y - yf;
      const int x0 = (int)xf, y0 = (int)yf;

      // x-pair slots: pair base xa covers columns (xa, xa+1)
      float wxl = 1.f - dx, wxh = dx;
      int xa;
      if (x0 >= 0 && x0 <= Wd - 2)      { xa = x0; }
      else if (x0 == -1)                { xa = 0;      wxl = dx;       wxh = 0.f; }
      else if (x0 == Wd - 1)            { xa = Wd - 2; wxl = 0.f;      wxh = 1.f - dx; }
      else                              { xa = 0;      wxl = 0.f;      wxh = 0.f; }

#pragma unroll
      for (int r = 0; r < 2; ++r) {
        const int yr = y0 + r;
        const float wy = r ? dy : (1.f - dy);
        const bool vy = (yr >= 0) && (yr < Wd);
        const float wl = vy ? wa * wy * wxl : 0.f;
        const float wh = vy ? wa * wy * wxh : 0.f;
        const int idx = lbase + (vy ? yr : 0) * Wd + xa;
        const unsigned int w2 = ((__float_as_uint(wl) + 0x8000u) & 0xffff0000u)
                              | ((__float_as_uint(wh) + 0x8000u) >> 16);
        cb[(p * 2 + r) * 2 + 0] = w2;
        cb[(p * 2 + r) * 2 + 1] = (unsigned)idx;
      }
    }
  }
  __syncthreads();

  const int lane = t & 63;
  const int wid  = t >> 6;

  // ---- gather: wave wid covers queries {2*wid, 2*wid+1} ----
  {
    const int q2 = lane >> 5;
    const int gh = (lane >> 2) & 7;
    const int gs = lane & 3;
    const int qw = wid * 2 + q2;       // 0..15
    const int rr = qw * 8 + gh;        // 0..127
    const char* vb = (const char*)value;
    const unsigned int voff0 = (unsigned int)bb * (NK * 512u) + (unsigned)(gh * 64 + gs * 16);
    const uint2* cb = (const uint2*)&combo[rr * CS];

    float a0=0.f,a1=0.f,a2=0.f,a3=0.f,a4=0.f,a5=0.f,a6=0.f,a7=0.f;
#pragma unroll 4
    for (int e = 0; e < 32; ++e) {
      const uint2 u = cb[e];
      const float wl = __uint_as_float(u.x & 0xffff0000u);
      const float wh = __uint_as_float(u.x << 16);
      const char* pv = vb + (size_t)(voff0 + (u.y << 9));
      const uint4 v0 = *(const uint4*)(pv);
      const uint4 v1 = *(const uint4*)(pv + 512);
      a0 += wl * __uint_as_float(v0.x << 16);
      a1 += wl * __uint_as_float(v0.x & 0xffff0000u);
      a2 += wl * __uint_as_float(v0.y << 16);
      a3 += wl * __uint_as_float(v0.y & 0xffff0000u);
      a4 += wl * __uint_as_float(v0.z << 16);
      a5 += wl * __uint_as_float(v0.z & 0xffff0000u);
      a6 += wl * __uint_as_float(v0.w << 16);
      a7 += wl * __uint_as_float(v0.w & 0xffff0000u);
      a0 += wh * __uint_as_float(v1.x << 16);
      a1 += wh * __uint_as_float(v1.x & 0xffff0000u);
      a2 += wh * __uint_as_float(v1.y << 16);
      a3 += wh * __uint_as_float(v1.y & 0xffff0000u);
      a4 += wh * __uint_as_float(v1.z << 16);
      a5 += wh * __uint_as_float(v1.z & 0xffff0000u);
      a6 += wh * __uint_as_float(v1.w << 16);
      a7 += wh * __uint_as_float(v1.w & 0xffff0000u);
    }
    // stash acc into this region's dead entries (16B-aligned slots)
    bf16x8 o;
    o[0]=(__bf16)a0; o[1]=(__bf16)a1; o[2]=(__bf16)a2; o[3]=(__bf16)a3;
    o[4]=(__bf16)a4; o[5]=(__bf16)a5; o[6]=(__bf16)a6; o[7]=(__bf16)a7;
    *(bf16x8*)(&combo[rr * CS + (rr & 1) * 2 + gs * 4]) = o;
  }
  __syncthreads();

  // ---- out-projection: out[16 x 256] = accs @ Wo + bo ----
  // A-frag: ql = lane&15, hi = lane>>4 (k-sub 0..3); ch8 = kt*4 + hi lives in
  // region rr = ql*8 + kt at u32 offset (rr&1)*2 + hi*4. Wave wid covers 32
  // cols: block cbk = wid>>1, sub-pair sp = wid&1.
  {
    const int ql = lane & 15;
    const int hi = lane >> 4;
    const unsigned int* abase = combo + ql * (8 * CS) + hi * 4;
    const int cbk = wid >> 1, sp = wid & 1;
    const bf16x8* bpn = wo_p + (size_t)cbk * 2048;
    f32x4 oacc[2] = {};
#pragma unroll
    for (int kt = 0; kt < 8; ++kt) {
      bf16x8 a = *(const bf16x8*)(abase + kt * CS + (kt & 1) * 2);
#pragma unroll
      for (int n = 0; n < 2; ++n)
        oacc[n] = mfma16(a, bpn[(kt * 4 + sp * 2 + n) * 64 + lane], oacc[n]);
    }
#pragma unroll
    for (int n = 0; n < 2; ++n) {
      const int col = cbk * 64 + sp * 32 + n * 16 + ql;
      const float bias = bo[col];
#pragma unroll
      for (int rg = 0; rg < 4; ++rg) {
        const int qi = hi * 4 + rg;
        const unsigned int qreal = qmap[qi];
        if (qreal != 0xFFFFFFFFu)
          outp[((size_t)bb * NQ + qreal) * 256 + col] = oacc[n][rg] + bias;
      }
    }
  }
}

extern "C" void kernel_launch(void* const* d_in, const int* in_sizes, int n_in,
                              void* d_out, int out_size, void* d_ws, size_t ws_size,
                              hipStream_t stream) {
  const float* query = (const float*)d_in[0];
  const float* refp  = (const float*)d_in[1];
  const float* inpf  = (const float*)d_in[2];
  const float* Wv    = (const float*)d_in[3];
  const float* bv    = (const float*)d_in[4];
  const float* Ws    = (const float*)d_in[5];
  const float* bs    = (const float*)d_in[6];
  const float* Wa    = (const float*)d_in[7];
  const float* ba    = (const float*)d_in[8];
  const float* Wo    = (const float*)d_in[9];
  const float* bo    = (const float*)d_in[10];
  float* out = (float*)d_out;

  char* w = (char*)d_ws;
  __hip_bfloat16* value  = (__hip_bfloat16*)w;            w += (size_t)(M_ + 1) * 256 * 2;  // +1 guard row
  __half*         params = (__half*)w;                    w += (size_t)M_ * 384 * 2;
  __hip_bfloat16* wv_p   = (__hip_bfloat16*)w;            w += 256 * 256 * 2;
  __hip_bfloat16* wsa_p  = (__hip_bfloat16*)w;            w += 256 * 384 * 2;
  __hip_bfloat16* wo_p   = (__hip_bfloat16*)w;            w += 256 * 256 * 2;
  unsigned int*   hist   = (unsigned int*)w;              w += 2048 * 4;
  unsigned int*   cursor = (unsigned int*)w;              w += 2048 * 4;
  unsigned int*   perm   = (unsigned int*)w;

  hipMemsetAsync(hist, 0, 2048 * 4, stream);

  const int sg = (2 * NQ + 255) / 256;  // 104
  hist_k<<<sg, 256, 0, stream>>>(refp, hist);
  scan_k<<<1, 256, 0, stream>>>(hist, cursor);
  scatter_k<<<sg, 256, 0, stream>>>(refp, cursor, perm);

  pack_all<<<112, 256, 0, stream>>>(Wv, Ws, Wa, Wo, wv_p, wsa_p, wo_p);

  gemm_mt<<<dim3(GX, 2), 128, 0, stream>>>(
      inpf, query, (const bf16x8*)wv_p, (const bf16x8*)wsa_p,
      bv, bs, ba, value, params);

  sampler<<<1664, 512, 0, stream>>>(refp, params, value,
                                    (const bf16x8*)wo_p, bo, perm, out);
}

// Round 15
// 116.637 us; speedup vs baseline: 1.1116x; 1.1116x over previous
//
#include <hip/hip_runtime.h>
#include <hip/hip_bf16.h>
#include <hip/hip_fp16.h>
#include <math.h>

#define B_  2
#define NQ  13294
#define NK  13294
#define M_  (B_ * NK)   // 26588
#define MT  32
#define GX  ((M_ + MT - 1) / MT)  // 831

typedef __bf16 bf16x8 __attribute__((ext_vector_type(8)));
typedef float f32x4 __attribute__((ext_vector_type(4)));

static __device__ __forceinline__ f32x4 mfma16(bf16x8 a, bf16x8 b, f32x4 c) {
  return __builtin_amdgcn_mfma_f32_16x16x32_bf16(a, b, c, 0, 0, 0);
}

// ---- pack weights f32 [K=256][N] -> bf16 MFMA B-fragment layout ----
static __device__ __forceinline__ void pack_one(
    const float* __restrict__ W1, const float* __restrict__ W2,
    int N1, int Ntot, __hip_bfloat16* __restrict__ out, int g) {
  int lane = g & 63;
  int n_sub = (g >> 6) & 3;
  int kt = (g >> 8) & 7;
  int bn = g >> 11;
  int n = bn * 64 + n_sub * 16 + (lane & 15);
  int k0 = kt * 32 + (lane >> 4) * 8;
  const float* src; int nn, Ns;
  if (n < N1) { src = W1; nn = n; Ns = N1; }
  else        { src = W2; nn = n - N1; Ns = Ntot - N1; }
  bf16x8 v;
#pragma unroll
  for (int j = 0; j < 8; ++j) v[j] = (__bf16)src[(size_t)(k0 + j) * Ns + nn];
  *(bf16x8*)(out + (size_t)g * 8) = v;
}

__global__ __launch_bounds__(256) void pack_all(
    const float* __restrict__ Wv, const float* __restrict__ Ws,
    const float* __restrict__ Wa, const float* __restrict__ Wo,
    __hip_bfloat16* __restrict__ wv_p, __hip_bfloat16* __restrict__ wsa_p,
    __hip_bfloat16* __restrict__ wo_p) {
  const int b = blockIdx.x, t = threadIdx.x;
  if (b < 32)       pack_one(Wv, Wv, 256, 256, wv_p,  b * 256 + t);
  else if (b < 80)  pack_one(Ws, Wa, 256, 384, wsa_p, (b - 32) * 256 + t);
  else              pack_one(Wo, Wo, 256, 256, wo_p,  (b - 80) * 256 + t);
}

// ---- query locality sort: bin by level-0 reference point (32x32 per batch) ----
static __device__ __forceinline__ int bin_of(const float* refp, int b, int q) {
  const size_t base = (((size_t)b * NQ + q) * 4) * 2;  // level 0
  float rx = refp[base + 0], ry = refp[base + 1];
  int bx = (int)(rx * 32.f); bx = bx < 0 ? 0 : (bx > 31 ? 31 : bx);
  int by = (int)(ry * 32.f); by = by < 0 ? 0 : (by > 31 ? 31 : by);
  return b * 1024 + by * 32 + bx;
}

__global__ __launch_bounds__(256) void hist_k(
    const float* __restrict__ refp, unsigned int* __restrict__ hist) {
  int i = blockIdx.x * 256 + threadIdx.x;
  if (i >= 2 * NQ) return;
  int b = i >= NQ; int q = i - b * NQ;
  atomicAdd(&hist[bin_of(refp, b, q)], 1u);
}

__global__ __launch_bounds__(256) void scan_k(
    const unsigned int* __restrict__ hist, unsigned int* __restrict__ cursor) {
  __shared__ unsigned int lds[256];
  const int t = threadIdx.x;
  unsigned int v[8], s = 0;
#pragma unroll
  for (int j = 0; j < 8; ++j) { v[j] = hist[t * 8 + j]; s += v[j]; }
  lds[t] = s; __syncthreads();
  for (int off = 1; off < 256; off <<= 1) {
    unsigned int x = (t >= off) ? lds[t - off] : 0u;
    __syncthreads();
    lds[t] += x;
    __syncthreads();
  }
  unsigned int base = lds[t] - s;
#pragma unroll
  for (int j = 0; j < 8; ++j) { cursor[t * 8 + j] = base; base += v[j]; }
}

__global__ __launch_bounds__(256) void scatter_k(
    const float* __restrict__ refp, unsigned int* __restrict__ cursor,
    unsigned int* __restrict__ perm) {
  int i = blockIdx.x * 256 + threadIdx.x;
  if (i >= 2 * NQ) return;
  int b = i >= NQ; int q = i - b * NQ;
  unsigned int pos = atomicAdd(&cursor[bin_of(refp, b, q)], 1u);
  perm[pos] = (unsigned int)q;
}

// ---- 32-row-tile GEMM (modes 0/1) ----
#define CSTR 68

__global__ __launch_bounds__(128) void gemm_mt(
    const float* __restrict__ inpf, const float* __restrict__ query,
    const bf16x8* __restrict__ wv_p, const bf16x8* __restrict__ wsa_p,
    const float* __restrict__ bv, const float* __restrict__ bs,
    const float* __restrict__ ba,
    __hip_bfloat16* __restrict__ value, __half* __restrict__ params) {
  __shared__ bf16x8 As[8 * 2 * 64];        // 16 KB
  __shared__ float  Cs[2 * MT * CSTR];     // 17.4 KB

  const int t = threadIdx.x;
  const int bm = blockIdx.x * MT;
  const int lane = t & 63, wid = t >> 6;
  const int mode = blockIdx.y;

  {
    const int r = t >> 2;
    const int row = bm + r;
    const int sm = r >> 4;
    const int lb = r & 15;
    const bool ok = row < M_;
    const float* Af = (mode == 0) ? inpf : query;
    const float* ap = Af + (size_t)row * 256 + (t & 3) * 64;
#pragma unroll
    for (int gi = 0; gi < 8; ++gi) {
      float4 u = make_float4(0.f,0.f,0.f,0.f), v = make_float4(0.f,0.f,0.f,0.f);
      if (ok) { u = *(const float4*)(ap + gi * 8); v = *(const float4*)(ap + gi * 8 + 4); }
      bf16x8 w;
      w[0]=(__bf16)u.x; w[1]=(__bf16)u.y; w[2]=(__bf16)u.z; w[3]=(__bf16)u.w;
      w[4]=(__bf16)v.x; w[5]=(__bf16)v.y; w[6]=(__bf16)v.z; w[7]=(__bf16)v.w;
      int k8 = (t & 3) * 8 + gi;
      As[((k8 >> 2) * 2 + sm) * 64 + lb + ((k8 & 3) << 4)] = w;
    }
  }
  __syncthreads();

  const bf16x8* Bp = (mode == 0) ? wv_p : wsa_p;
  const int NB = (mode == 1) ? 6 : 4;
  float* Cw = &Cs[wid * MT * CSTR];

  for (int nb = wid; nb < NB; nb += 2) {
    const int colbase = nb * 64;
    const bf16x8* bpn = Bp + (size_t)nb * 2048;

    f32x4 acc[2][4] = {};
#pragma unroll
    for (int kt = 0; kt < 8; ++kt) {
      bf16x8 a0 = As[(kt * 2 + 0) * 64 + lane];
      bf16x8 a1 = As[(kt * 2 + 1) * 64 + lane];
#pragma unroll
      for (int n = 0; n < 4; ++n) {
        bf16x8 b = bpn[(kt * 4 + n) * 64 + lane];
        acc[0][n] = mfma16(a0, b, acc[0][n]);
        acc[1][n] = mfma16(a1, b, acc[1][n]);
      }
    }

#pragma unroll
    for (int m = 0; m < 2; ++m)
#pragma unroll
      for (int n = 0; n < 4; ++n)
#pragma unroll
        for (int rg = 0; rg < 4; ++rg)
          Cw[(m * 16 + (lane >> 4) * 4 + rg) * CSTR + n * 16 + (lane & 15)] = acc[m][n][rg];

    if (mode == 0) {
#pragma unroll
      for (int p = 0; p < 4; ++p) {
        const int r = (lane >> 3) + p * 8;
        const int c = (lane & 7) * 8;
        const int row = bm + r;
        float4 u = *(float4*)&Cw[r * CSTR + c];
        float4 v = *(float4*)&Cw[r * CSTR + c + 4];
        const float* bias = bv + colbase + c;
        bf16x8 o;
        o[0]=(__bf16)(u.x+bias[0]); o[1]=(__bf16)(u.y+bias[1]);
        o[2]=(__bf16)(u.z+bias[2]); o[3]=(__bf16)(u.w+bias[3]);
        o[4]=(__bf16)(v.x+bias[4]); o[5]=(__bf16)(v.y+bias[5]);
        o[6]=(__bf16)(v.z+bias[6]); o[7]=(__bf16)(v.w+bias[7]);
        if (row < M_)
          *(bf16x8*)(value + (size_t)row * 256 + colbase + c) = o;
      }
    } else {
#pragma unroll
      for (int p = 0; p < 8; ++p) {
        const int r = (lane >> 4) + p * 4;
        const int c = (lane & 15) * 4;
        const int row = bm + r;
        const int col = colbase + c;
        float4 u = *(float4*)&Cw[r * CSTR + c];
        const float* bias = (col < 256) ? (bs + col) : (ba + col - 256);
        u.x += bias[0]; u.y += bias[1]; u.z += bias[2]; u.w += bias[3];
        if (row < M_) {
          __half2 h0 = __floats2half2_rn(u.x, u.y);
          __half2 h1 = __floats2half2_rn(u.z, u.w);
          uint2 st;
          st.x = *(unsigned int*)&h0;
          st.y = *(unsigned int*)&h1;
          *(uint2*)(params + (size_t)row * 384 + col) = st;
        }
      }
    }
  }
}

// ---- fused sampler: 512 threads, 16 queries, pair-entry combo ----
// __launch_bounds__(512, 3): under CUDA blocks-interp -> 3 blocks/CU = 24
// waves, VGPR cap ~85; under waves-interp -> cap ~170. Either way no spill
// (R13/R14: (512,8)/(512,6) both produced cap-64 spill: VGPR=28, +57MB
// scratch writes). Gather unroll 2 (was 4) trims live-range pressure.
#define CS 66

__global__ __launch_bounds__(512, 3) void sampler(
    const float* __restrict__ refp, const __half* __restrict__ params,
    const __hip_bfloat16* __restrict__ value, const bf16x8* __restrict__ wo_p,
    const float* __restrict__ bo, const unsigned int* __restrict__ perm,
    float* __restrict__ outp) {
  __shared__ unsigned int combo[128 * CS];  // 33.8 KB
  __shared__ unsigned int qmap[16];

  const int c  = blockIdx.x & 7;
  const int kk = blockIdx.x >> 3;
  const int bb = c >> 2;
  const int qb = (c & 3) * 208 + kk;  // 0..831
  const int q0 = qb * 16;

  const int t = threadIdx.x;
  if (t < 16)
    qmap[t] = (q0 + t < NQ) ? perm[(size_t)bb * NQ + q0 + t] : 0xFFFFFFFFu;
  __syncthreads();

  // ---- build: one thread per (q, head, level): 16*8*4 = 512 ----
  {
    const int cqi = t >> 5;
    const int chh = (t >> 2) & 7;
    const int cl  = t & 3;
    const float DIMF[4]  = {100.f, 50.f, 25.f, 13.f};
    const int   LSTART[4] = {0, 10000, 12500, 13125};
    const float dimf  = DIMF[cl];
    const int   Wd    = (int)dimf;
    const int   lbase = LSTART[cl];

    const unsigned int qreal = qmap[cqi];
    const bool valid = qreal != 0xFFFFFFFFu;
    const size_t row = (size_t)bb * NQ + (valid ? qreal : 0);
    const __half* pr = params + row * 384;

    union { uint4 u[2]; __half h[16]; } LG;
    LG.u[0] = *(const uint4*)(pr + 256 + chh * 16);
    LG.u[1] = *(const uint4*)(pr + 256 + chh * 16 + 8);
    float lgf[16];
#pragma unroll
    for (int j = 0; j < 16; ++j) lgf[j] = __half2float(LG.h[j]);
    float m = lgf[0];
#pragma unroll
    for (int j = 1; j < 16; ++j) m = fmaxf(m, lgf[j]);
    float s = 0.f;
#pragma unroll
    for (int j = 0; j < 16; ++j) s += __expf(lgf[j] - m);
    const float inv = valid ? 1.f / s : 0.f;

    const float rx = refp[(row * 4 + cl) * 2 + 0];
    const float ry = refp[(row * 4 + cl) * 2 + 1];
    union { uint4 u; __half h[8]; } OF;
    OF.u = *(const uint4*)(pr + chh * 32 + cl * 8);
    unsigned int* cb = &combo[(cqi * 8 + chh) * CS + cl * 16];

#pragma unroll
    for (int p = 0; p < 4; ++p) {
      const float wa = __expf(lgf[cl * 4 + p] - m) * inv;
      const float x = rx * dimf + __half2float(OF.h[p * 2 + 0]) - 0.5f;
      const float y = ry * dimf + __half2float(OF.h[p * 2 + 1]) - 0.5f;
      const float xf = floorf(x), yf = floorf(y);
      const float dx = x - xf, dy = y - yf;
      const int x0 = (int)xf, y0 = (int)yf;

      // x-pair slots: pair base xa covers columns (xa, xa+1)
      float wxl = 1.f - dx, wxh = dx;
      int xa;
      if (x0 >= 0 && x0 <= Wd - 2)      { xa = x0; }
      else if (x0 == -1)                { xa = 0;      wxl = dx;       wxh = 0.f; }
      else if (x0 == Wd - 1)            { xa = Wd - 2; wxl = 0.f;      wxh = 1.f - dx; }
      else                              { xa = 0;      wxl = 0.f;      wxh = 0.f; }

#pragma unroll
      for (int r = 0; r < 2; ++r) {
        const int yr = y0 + r;
        const float wy = r ? dy : (1.f - dy);
        const bool vy = (yr >= 0) && (yr < Wd);
        const float wl = vy ? wa * wy * wxl : 0.f;
        const float wh = vy ? wa * wy * wxh : 0.f;
        const int idx = lbase + (vy ? yr : 0) * Wd + xa;
        const unsigned int w2 = ((__float_as_uint(wl) + 0x8000u) & 0xffff0000u)
                              | ((__float_as_uint(wh) + 0x8000u) >> 16);
        cb[(p * 2 + r) * 2 + 0] = w2;
        cb[(p * 2 + r) * 2 + 1] = (unsigned)idx;
      }
    }
  }
  __syncthreads();

  const int lane = t & 63;
  const int wid  = t >> 6;

  // ---- gather: wave wid covers queries {2*wid, 2*wid+1} ----
  {
    const int q2 = lane >> 5;
    const int gh = (lane >> 2) & 7;
    const int gs = lane & 3;
    const int qw = wid * 2 + q2;       // 0..15
    const int rr = qw * 8 + gh;        // 0..127
    const char* vb = (const char*)value;
    const unsigned int voff0 = (unsigned int)bb * (NK * 512u) + (unsigned)(gh * 64 + gs * 16);
    const uint2* cb = (const uint2*)&combo[rr * CS];

    float a0=0.f,a1=0.f,a2=0.f,a3=0.f,a4=0.f,a5=0.f,a6=0.f,a7=0.f;
#pragma unroll 2
    for (int e = 0; e < 32; ++e) {
      const uint2 u = cb[e];
      const float wl = __uint_as_float(u.x & 0xffff0000u);
      const float wh = __uint_as_float(u.x << 16);
      const char* pv = vb + (size_t)(voff0 + (u.y << 9));
      const uint4 v0 = *(const uint4*)(pv);
      const uint4 v1 = *(const uint4*)(pv + 512);
      a0 += wl * __uint_as_float(v0.x << 16);
      a1 += wl * __uint_as_float(v0.x & 0xffff0000u);
      a2 += wl * __uint_as_float(v0.y << 16);
      a3 += wl * __uint_as_float(v0.y & 0xffff0000u);
      a4 += wl * __uint_as_float(v0.z << 16);
      a5 += wl * __uint_as_float(v0.z & 0xffff0000u);
      a6 += wl * __uint_as_float(v0.w << 16);
      a7 += wl * __uint_as_float(v0.w & 0xffff0000u);
      a0 += wh * __uint_as_float(v1.x << 16);
      a1 += wh * __uint_as_float(v1.x & 0xffff0000u);
      a2 += wh * __uint_as_float(v1.y << 16);
      a3 += wh * __uint_as_float(v1.y & 0xffff0000u);
      a4 += wh * __uint_as_float(v1.z << 16);
      a5 += wh * __uint_as_float(v1.z & 0xffff0000u);
      a6 += wh * __uint_as_float(v1.w << 16);
      a7 += wh * __uint_as_float(v1.w & 0xffff0000u);
    }
    // stash acc into this region's dead entries (16B-aligned slots)
    bf16x8 o;
    o[0]=(__bf16)a0; o[1]=(__bf16)a1; o[2]=(__bf16)a2; o[3]=(__bf16)a3;
    o[4]=(__bf16)a4; o[5]=(__bf16)a5; o[6]=(__bf16)a6; o[7]=(__bf16)a7;
    *(bf16x8*)(&combo[rr * CS + (rr & 1) * 2 + gs * 4]) = o;
  }
  __syncthreads();

  // ---- out-projection: out[16 x 256] = accs @ Wo + bo ----
  // A-frag: ql = lane&15, hi = lane>>4 (k-sub 0..3); ch8 = kt*4 + hi lives in
  // region rr = ql*8 + kt at u32 offset (rr&1)*2 + hi*4. Wave wid covers 32
  // cols: block cbk = wid>>1, sub-pair sp = wid&1.
  {
    const int ql = lane & 15;
    const int hi = lane >> 4;
    const unsigned int* abase = combo + ql * (8 * CS) + hi * 4;
    const int cbk = wid >> 1, sp = wid & 1;
    const bf16x8* bpn = wo_p + (size_t)cbk * 2048;
    f32x4 oacc[2] = {};
#pragma unroll
    for (int kt = 0; kt < 8; ++kt) {
      bf16x8 a = *(const bf16x8*)(abase + kt * CS + (kt & 1) * 2);
#pragma unroll
      for (int n = 0; n < 2; ++n)
        oacc[n] = mfma16(a, bpn[(kt * 4 + sp * 2 + n) * 64 + lane], oacc[n]);
    }
#pragma unroll
    for (int n = 0; n < 2; ++n) {
      const int col = cbk * 64 + sp * 32 + n * 16 + ql;
      const float bias = bo[col];
#pragma unroll
      for (int rg = 0; rg < 4; ++rg) {
        const int qi = hi * 4 + rg;
        const unsigned int qreal = qmap[qi];
        if (qreal != 0xFFFFFFFFu)
          outp[((size_t)bb * NQ + qreal) * 256 + col] = oacc[n][rg] + bias;
      }
    }
  }
}

extern "C" void kernel_launch(void* const* d_in, const int* in_sizes, int n_in,
                              void* d_out, int out_size, void* d_ws, size_t ws_size,
                              hipStream_t stream) {
  const float* query = (const float*)d_in[0];
  const float* refp  = (const float*)d_in[1];
  const float* inpf  = (const float*)d_in[2];
  const float* Wv    = (const float*)d_in[3];
  const float* bv    = (const float*)d_in[4];
  const float* Ws    = (const float*)d_in[5];
  const float* bs    = (const float*)d_in[6];
  const float* Wa    = (const float*)d_in[7];
  const float* ba    = (const float*)d_in[8];
  const float* Wo    = (const float*)d_in[9];
  const float* bo    = (const float*)d_in[10];
  float* out = (float*)d_out;

  char* w = (char*)d_ws;
  __hip_bfloat16* value  = (__hip_bfloat16*)w;            w += (size_t)(M_ + 1) * 256 * 2;  // +1 guard row
  __half*         params = (__half*)w;                    w += (size_t)M_ * 384 * 2;
  __hip_bfloat16* wv_p   = (__hip_bfloat16*)w;            w += 256 * 256 * 2;
  __hip_bfloat16* wsa_p  = (__hip_bfloat16*)w;            w += 256 * 384 * 2;
  __hip_bfloat16* wo_p   = (__hip_bfloat16*)w;            w += 256 * 256 * 2;
  unsigned int*   hist   = (unsigned int*)w;              w += 2048 * 4;
  unsigned int*   cursor = (unsigned int*)w;              w += 2048 * 4;
  unsigned int*   perm   = (unsigned int*)w;

  hipMemsetAsync(hist, 0, 2048 * 4, stream);

  const int sg = (2 * NQ + 255) / 256;  // 104
  hist_k<<<sg, 256, 0, stream>>>(refp, hist);
  scan_k<<<1, 256, 0, stream>>>(hist, cursor);
  scatter_k<<<sg, 256, 0, stream>>>(refp, cursor, perm);

  pack_all<<<112, 256, 0, stream>>>(Wv, Ws, Wa, Wo, wv_p, wsa_p, wo_p);

  gemm_mt<<<dim3(GX, 2), 128, 0, stream>>>(
      inpf, query, (const bf16x8*)wv_p, (const bf16x8*)wsa_p,
      bv, bs, ba, value, params);

  sampler<<<1664, 512, 0, stream>>>(refp, params, value,
                                    (const bf16x8*)wo_p, bo, perm, out);
}

// Round 16
// 116.251 us; speedup vs baseline: 1.1153x; 1.0033x over previous
//
#include <hip/hip_runtime.h>
#include <hip/hip_bf16.h>
#include <hip/hip_fp16.h>
#include <math.h>

#define B_  2
#define NQ  13294
#define NK  13294
#define M_  (B_ * NK)   // 26588
#define MT  32
#define GX  ((M_ + MT - 1) / MT)  // 831

typedef __bf16 bf16x8 __attribute__((ext_vector_type(8)));
typedef float f32x4 __attribute__((ext_vector_type(4)));

static __device__ __forceinline__ f32x4 mfma16(bf16x8 a, bf16x8 b, f32x4 c) {
  return __builtin_amdgcn_mfma_f32_16x16x32_bf16(a, b, c, 0, 0, 0);
}

// ---- pack weights f32 [K=256][N] -> bf16 MFMA B-fragment layout ----
static __device__ __forceinline__ void pack_one(
    const float* __restrict__ W1, const float* __restrict__ W2,
    int N1, int Ntot, __hip_bfloat16* __restrict__ out, int g) {
  int lane = g & 63;
  int n_sub = (g >> 6) & 3;
  int kt = (g >> 8) & 7;
  int bn = g >> 11;
  int n = bn * 64 + n_sub * 16 + (lane & 15);
  int k0 = kt * 32 + (lane >> 4) * 8;
  const float* src; int nn, Ns;
  if (n < N1) { src = W1; nn = n; Ns = N1; }
  else        { src = W2; nn = n - N1; Ns = Ntot - N1; }
  bf16x8 v;
#pragma unroll
  for (int j = 0; j < 8; ++j) v[j] = (__bf16)src[(size_t)(k0 + j) * Ns + nn];
  *(bf16x8*)(out + (size_t)g * 8) = v;
}

__global__ __launch_bounds__(256) void pack_all(
    const float* __restrict__ Wv, const float* __restrict__ Ws,
    const float* __restrict__ Wa, const float* __restrict__ Wo,
    __hip_bfloat16* __restrict__ wv_p, __hip_bfloat16* __restrict__ wsa_p,
    __hip_bfloat16* __restrict__ wo_p) {
  const int b = blockIdx.x, t = threadIdx.x;
  if (b < 32)       pack_one(Wv, Wv, 256, 256, wv_p,  b * 256 + t);
  else if (b < 80)  pack_one(Ws, Wa, 256, 384, wsa_p, (b - 32) * 256 + t);
  else              pack_one(Wo, Wo, 256, 256, wo_p,  (b - 80) * 256 + t);
}

// ---- query locality sort: bin by level-0 reference point (32x32 per batch) ----
static __device__ __forceinline__ int bin_of(const float* refp, int b, int q) {
  const size_t base = (((size_t)b * NQ + q) * 4) * 2;  // level 0
  float rx = refp[base + 0], ry = refp[base + 1];
  int bx = (int)(rx * 32.f); bx = bx < 0 ? 0 : (bx > 31 ? 31 : bx);
  int by = (int)(ry * 32.f); by = by < 0 ? 0 : (by > 31 ? 31 : by);
  return b * 1024 + by * 32 + bx;
}

__global__ __launch_bounds__(256) void hist_k(
    const float* __restrict__ refp, unsigned int* __restrict__ hist) {
  int i = blockIdx.x * 256 + threadIdx.x;
  if (i >= 2 * NQ) return;
  int b = i >= NQ; int q = i - b * NQ;
  atomicAdd(&hist[bin_of(refp, b, q)], 1u);
}

__global__ __launch_bounds__(256) void scan_k(
    const unsigned int* __restrict__ hist, unsigned int* __restrict__ cursor) {
  __shared__ unsigned int lds[256];
  const int t = threadIdx.x;
  unsigned int v[8], s = 0;
#pragma unroll
  for (int j = 0; j < 8; ++j) { v[j] = hist[t * 8 + j]; s += v[j]; }
  lds[t] = s; __syncthreads();
  for (int off = 1; off < 256; off <<= 1) {
    unsigned int x = (t >= off) ? lds[t - off] : 0u;
    __syncthreads();
    lds[t] += x;
    __syncthreads();
  }
  unsigned int base = lds[t] - s;
#pragma unroll
  for (int j = 0; j < 8; ++j) { cursor[t * 8 + j] = base; base += v[j]; }
}

__global__ __launch_bounds__(256) void scatter_k(
    const float* __restrict__ refp, unsigned int* __restrict__ cursor,
    unsigned int* __restrict__ perm) {
  int i = blockIdx.x * 256 + threadIdx.x;
  if (i >= 2 * NQ) return;
  int b = i >= NQ; int q = i - b * NQ;
  unsigned int pos = atomicAdd(&cursor[bin_of(refp, b, q)], 1u);
  perm[pos] = (unsigned int)q;
}

// ---- 32-row-tile GEMM (modes 0/1) ----
// LDS trimmed to 24.5 KB (As 16K + per-wave 16-row Cs 8.7K) -> 6 blocks/CU
// (12 waves/CU, was 8). Epilogue runs in two 16-row wave-private passes.
#define CSTR 68

__global__ __launch_bounds__(128) void gemm_mt(
    const float* __restrict__ inpf, const float* __restrict__ query,
    const bf16x8* __restrict__ wv_p, const bf16x8* __restrict__ wsa_p,
    const float* __restrict__ bv, const float* __restrict__ bs,
    const float* __restrict__ ba,
    __hip_bfloat16* __restrict__ value, __half* __restrict__ params) {
  __shared__ bf16x8 As[8 * 2 * 64];        // 16 KB
  __shared__ float  Cs[2 * 16 * CSTR];     // 8.7 KB (per-wave 16x68)

  const int t = threadIdx.x;
  const int bm = blockIdx.x * MT;
  const int lane = t & 63, wid = t >> 6;
  const int mode = blockIdx.y;

  {
    const int r = t >> 2;
    const int row = bm + r;
    const int sm = r >> 4;
    const int lb = r & 15;
    const bool ok = row < M_;
    const float* Af = (mode == 0) ? inpf : query;
    const float* ap = Af + (size_t)row * 256 + (t & 3) * 64;
#pragma unroll
    for (int gi = 0; gi < 8; ++gi) {
      float4 u = make_float4(0.f,0.f,0.f,0.f), v = make_float4(0.f,0.f,0.f,0.f);
      if (ok) { u = *(const float4*)(ap + gi * 8); v = *(const float4*)(ap + gi * 8 + 4); }
      bf16x8 w;
      w[0]=(__bf16)u.x; w[1]=(__bf16)u.y; w[2]=(__bf16)u.z; w[3]=(__bf16)u.w;
      w[4]=(__bf16)v.x; w[5]=(__bf16)v.y; w[6]=(__bf16)v.z; w[7]=(__bf16)v.w;
      int k8 = (t & 3) * 8 + gi;
      As[((k8 >> 2) * 2 + sm) * 64 + lb + ((k8 & 3) << 4)] = w;
    }
  }
  __syncthreads();

  const bf16x8* Bp = (mode == 0) ? wv_p : wsa_p;
  const int NB = (mode == 1) ? 6 : 4;
  float* Cw = &Cs[wid * 16 * CSTR];

  for (int nb = wid; nb < NB; nb += 2) {
    const int colbase = nb * 64;
    const bf16x8* bpn = Bp + (size_t)nb * 2048;

    f32x4 acc[2][4] = {};
#pragma unroll
    for (int kt = 0; kt < 8; ++kt) {
      bf16x8 a0 = As[(kt * 2 + 0) * 64 + lane];
      bf16x8 a1 = As[(kt * 2 + 1) * 64 + lane];
#pragma unroll
      for (int n = 0; n < 4; ++n) {
        bf16x8 b = bpn[(kt * 4 + n) * 64 + lane];
        acc[0][n] = mfma16(a0, b, acc[0][n]);
        acc[1][n] = mfma16(a1, b, acc[1][n]);
      }
    }

    // epilogue: two 16-row wave-private passes through Cw (no barriers)
#pragma unroll
    for (int m = 0; m < 2; ++m) {
#pragma unroll
      for (int n = 0; n < 4; ++n)
#pragma unroll
        for (int rg = 0; rg < 4; ++rg)
          Cw[((lane >> 4) * 4 + rg) * CSTR + n * 16 + (lane & 15)] = acc[m][n][rg];

      const int r = lane >> 2;          // 0..15
      const int c0 = (lane & 3) * 16;   // 0,16,32,48
      const int row = bm + m * 16 + r;
      const int col = colbase + c0;
      float vv[16];
      *(float4*)&vv[0]  = *(float4*)&Cw[r * CSTR + c0 + 0];
      *(float4*)&vv[4]  = *(float4*)&Cw[r * CSTR + c0 + 4];
      *(float4*)&vv[8]  = *(float4*)&Cw[r * CSTR + c0 + 8];
      *(float4*)&vv[12] = *(float4*)&Cw[r * CSTR + c0 + 12];

      if (mode == 0) {
        const float* bias = bv + col;
        bf16x8 o0, o1;
#pragma unroll
        for (int j = 0; j < 8; ++j) {
          o0[j] = (__bf16)(vv[j] + bias[j]);
          o1[j] = (__bf16)(vv[8 + j] + bias[8 + j]);
        }
        if (row < M_) {
          *(bf16x8*)(value + (size_t)row * 256 + col + 0) = o0;
          *(bf16x8*)(value + (size_t)row * 256 + col + 8) = o1;
        }
      } else {
        const float* bias = (col < 256) ? (bs + col) : (ba + col - 256);
        uint4 st0, st1;
        __half2 h;
        h = __floats2half2_rn(vv[0] + bias[0],  vv[1] + bias[1]);  st0.x = *(unsigned*)&h;
        h = __floats2half2_rn(vv[2] + bias[2],  vv[3] + bias[3]);  st0.y = *(unsigned*)&h;
        h = __floats2half2_rn(vv[4] + bias[4],  vv[5] + bias[5]);  st0.z = *(unsigned*)&h;
        h = __floats2half2_rn(vv[6] + bias[6],  vv[7] + bias[7]);  st0.w = *(unsigned*)&h;
        h = __floats2half2_rn(vv[8] + bias[8],  vv[9] + bias[9]);  st1.x = *(unsigned*)&h;
        h = __floats2half2_rn(vv[10] + bias[10], vv[11] + bias[11]); st1.y = *(unsigned*)&h;
        h = __floats2half2_rn(vv[12] + bias[12], vv[13] + bias[13]); st1.z = *(unsigned*)&h;
        h = __floats2half2_rn(vv[14] + bias[14], vv[15] + bias[15]); st1.w = *(unsigned*)&h;
        if (row < M_) {
          *(uint4*)(params + (size_t)row * 384 + col + 0) = st0;
          *(uint4*)(params + (size_t)row * 384 + col + 8) = st1;
        }
      }
    }
  }
}

// ---- fused sampler: 512 threads, 16 queries, pair-entry combo ----
// (512,3) + gather unroll 2: no scratch spill (R15: WRITE back to 31 MB),
// occupancy ~68%. Dead-slot acc stash -> MFMA out-projection.
#define CS 66

__global__ __launch_bounds__(512, 3) void sampler(
    const float* __restrict__ refp, const __half* __restrict__ params,
    const __hip_bfloat16* __restrict__ value, const bf16x8* __restrict__ wo_p,
    const float* __restrict__ bo, const unsigned int* __restrict__ perm,
    float* __restrict__ outp) {
  __shared__ unsigned int combo[128 * CS];  // 33.8 KB
  __shared__ unsigned int qmap[16];

  const int c  = blockIdx.x & 7;
  const int kk = blockIdx.x >> 3;
  const int bb = c >> 2;
  const int qb = (c & 3) * 208 + kk;  // 0..831
  const int q0 = qb * 16;

  const int t = threadIdx.x;
  if (t < 16)
    qmap[t] = (q0 + t < NQ) ? perm[(size_t)bb * NQ + q0 + t] : 0xFFFFFFFFu;
  __syncthreads();

  // ---- build: one thread per (q, head, level): 16*8*4 = 512 ----
  {
    const int cqi = t >> 5;
    const int chh = (t >> 2) & 7;
    const int cl  = t & 3;
    const float DIMF[4]  = {100.f, 50.f, 25.f, 13.f};
    const int   LSTART[4] = {0, 10000, 12500, 13125};
    const float dimf  = DIMF[cl];
    const int   Wd    = (int)dimf;
    const int   lbase = LSTART[cl];

    const unsigned int qreal = qmap[cqi];
    const bool valid = qreal != 0xFFFFFFFFu;
    const size_t row = (size_t)bb * NQ + (valid ? qreal : 0);
    const __half* pr = params + row * 384;

    union { uint4 u[2]; __half h[16]; } LG;
    LG.u[0] = *(const uint4*)(pr + 256 + chh * 16);
    LG.u[1] = *(const uint4*)(pr + 256 + chh * 16 + 8);
    float lgf[16];
#pragma unroll
    for (int j = 0; j < 16; ++j) lgf[j] = __half2float(LG.h[j]);
    float m = lgf[0];
#pragma unroll
    for (int j = 1; j < 16; ++j) m = fmaxf(m, lgf[j]);
    float s = 0.f;
#pragma unroll
    for (int j = 0; j < 16; ++j) s += __expf(lgf[j] - m);
    const float inv = valid ? 1.f / s : 0.f;

    const float rx = refp[(row * 4 + cl) * 2 + 0];
    const float ry = refp[(row * 4 + cl) * 2 + 1];
    union { uint4 u; __half h[8]; } OF;
    OF.u = *(const uint4*)(pr + chh * 32 + cl * 8);
    unsigned int* cb = &combo[(cqi * 8 + chh) * CS + cl * 16];

#pragma unroll
    for (int p = 0; p < 4; ++p) {
      const float wa = __expf(lgf[cl * 4 + p] - m) * inv;
      const float x = rx * dimf + __half2float(OF.h[p * 2 + 0]) - 0.5f;
      const float y = ry * dimf + __half2float(OF.h[p * 2 + 1]) - 0.5f;
      const float xf = floorf(x), yf = floorf(y);
      const float dx = x - xf, dy = y - yf;
      const int x0 = (int)xf, y0 = (int)yf;

      // x-pair slots: pair base xa covers columns (xa, xa+1)
      float wxl = 1.f - dx, wxh = dx;
      int xa;
      if (x0 >= 0 && x0 <= Wd - 2)      { xa = x0; }
      else if (x0 == -1)                { xa = 0;      wxl = dx;       wxh = 0.f; }
      else if (x0 == Wd - 1)            { xa = Wd - 2; wxl = 0.f;      wxh = 1.f - dx; }
      else                              { xa = 0;      wxl = 0.f;      wxh = 0.f; }

#pragma unroll
      for (int r = 0; r < 2; ++r) {
        const int yr = y0 + r;
        const float wy = r ? dy : (1.f - dy);
        const bool vy = (yr >= 0) && (yr < Wd);
        const float wl = vy ? wa * wy * wxl : 0.f;
        const float wh = vy ? wa * wy * wxh : 0.f;
        const int idx = lbase + (vy ? yr : 0) * Wd + xa;
        const unsigned int w2 = ((__float_as_uint(wl) + 0x8000u) & 0xffff0000u)
                              | ((__float_as_uint(wh) + 0x8000u) >> 16);
        cb[(p * 2 + r) * 2 + 0] = w2;
        cb[(p * 2 + r) * 2 + 1] = (unsigned)idx;
      }
    }
  }
  __syncthreads();

  const int lane = t & 63;
  const int wid  = t >> 6;

  // ---- gather: wave wid covers queries {2*wid, 2*wid+1} ----
  {
    const int q2 = lane >> 5;
    const int gh = (lane >> 2) & 7;
    const int gs = lane & 3;
    const int qw = wid * 2 + q2;       // 0..15
    const int rr = qw * 8 + gh;        // 0..127
    const char* vb = (const char*)value;
    const unsigned int voff0 = (unsigned int)bb * (NK * 512u) + (unsigned)(gh * 64 + gs * 16);
    const uint2* cb = (const uint2*)&combo[rr * CS];

    float a0=0.f,a1=0.f,a2=0.f,a3=0.f,a4=0.f,a5=0.f,a6=0.f,a7=0.f;
#pragma unroll 2
    for (int e = 0; e < 32; ++e) {
      const uint2 u = cb[e];
      const float wl = __uint_as_float(u.x & 0xffff0000u);
      const float wh = __uint_as_float(u.x << 16);
      const char* pv = vb + (size_t)(voff0 + (u.y << 9));
      const uint4 v0 = *(const uint4*)(pv);
      const uint4 v1 = *(const uint4*)(pv + 512);
      a0 += wl * __uint_as_float(v0.x << 16);
      a1 += wl * __uint_as_float(v0.x & 0xffff0000u);
      a2 += wl * __uint_as_float(v0.y << 16);
      a3 += wl * __uint_as_float(v0.y & 0xffff0000u);
      a4 += wl * __uint_as_float(v0.z << 16);
      a5 += wl * __uint_as_float(v0.z & 0xffff0000u);
      a6 += wl * __uint_as_float(v0.w << 16);
      a7 += wl * __uint_as_float(v0.w & 0xffff0000u);
      a0 += wh * __uint_as_float(v1.x << 16);
      a1 += wh * __uint_as_float(v1.x & 0xffff0000u);
      a2 += wh * __uint_as_float(v1.y << 16);
      a3 += wh * __uint_as_float(v1.y & 0xffff0000u);
      a4 += wh * __uint_as_float(v1.z << 16);
      a5 += wh * __uint_as_float(v1.z & 0xffff0000u);
      a6 += wh * __uint_as_float(v1.w << 16);
      a7 += wh * __uint_as_float(v1.w & 0xffff0000u);
    }
    // stash acc into this region's dead entries (16B-aligned slots)
    bf16x8 o;
    o[0]=(__bf16)a0; o[1]=(__bf16)a1; o[2]=(__bf16)a2; o[3]=(__bf16)a3;
    o[4]=(__bf16)a4; o[5]=(__bf16)a5; o[6]=(__bf16)a6; o[7]=(__bf16)a7;
    *(bf16x8*)(&combo[rr * CS + (rr & 1) * 2 + gs * 4]) = o;
  }
  __syncthreads();

  // ---- out-projection: out[16 x 256] = accs @ Wo + bo ----
  {
    const int ql = lane & 15;
    const int hi = lane >> 4;
    const unsigned int* abase = combo + ql * (8 * CS) + hi * 4;
    const int cbk = wid >> 1, sp = wid & 1;
    const bf16x8* bpn = wo_p + (size_t)cbk * 2048;
    f32x4 oacc[2] = {};
#pragma unroll
    for (int kt = 0; kt < 8; ++kt) {
      bf16x8 a = *(const bf16x8*)(abase + kt * CS + (kt & 1) * 2);
#pragma unroll
      for (int n = 0; n < 2; ++n)
        oacc[n] = mfma16(a, bpn[(kt * 4 + sp * 2 + n) * 64 + lane], oacc[n]);
    }
#pragma unroll
    for (int n = 0; n < 2; ++n) {
      const int col = cbk * 64 + sp * 32 + n * 16 + ql;
      const float bias = bo[col];
#pragma unroll
      for (int rg = 0; rg < 4; ++rg) {
        const int qi = hi * 4 + rg;
        const unsigned int qreal = qmap[qi];
        if (qreal != 0xFFFFFFFFu)
          outp[((size_t)bb * NQ + qreal) * 256 + col] = oacc[n][rg] + bias;
      }
    }
  }
}

extern "C" void kernel_launch(void* const* d_in, const int* in_sizes, int n_in,
                              void* d_out, int out_size, void* d_ws, size_t ws_size,
                              hipStream_t stream) {
  const float* query = (const float*)d_in[0];
  const float* refp  = (const float*)d_in[1];
  const float* inpf  = (const float*)d_in[2];
  const float* Wv    = (const float*)d_in[3];
  const float* bv    = (const float*)d_in[4];
  const float* Ws    = (const float*)d_in[5];
  const float* bs    = (const float*)d_in[6];
  const float* Wa    = (const float*)d_in[7];
  const float* ba    = (const float*)d_in[8];
  const float* Wo    = (const float*)d_in[9];
  const float* bo    = (const float*)d_in[10];
  float* out = (float*)d_out;

  char* w = (char*)d_ws;
  __hip_bfloat16* value  = (__hip_bfloat16*)w;            w += (size_t)(M_ + 1) * 256 * 2;  // +1 guard row
  __half*         params = (__half*)w;                    w += (size_t)M_ * 384 * 2;
  __hip_bfloat16* wv_p   = (__hip_bfloat16*)w;            w += 256 * 256 * 2;
  __hip_bfloat16* wsa_p  = (__hip_bfloat16*)w;            w += 256 * 384 * 2;
  __hip_bfloat16* wo_p   = (__hip_bfloat16*)w;            w += 256 * 256 * 2;
  unsigned int*   hist   = (unsigned int*)w;              w += 2048 * 4;
  unsigned int*   cursor = (unsigned int*)w;              w += 2048 * 4;
  unsigned int*   perm   = (unsigned int*)w;

  hipMemsetAsync(hist, 0, 2048 * 4, stream);

  const int sg = (2 * NQ + 255) / 256;  // 104
  hist_k<<<sg, 256, 0, stream>>>(refp, hist);
  scan_k<<<1, 256, 0, stream>>>(hist, cursor);
  scatter_k<<<sg, 256, 0, stream>>>(refp, cursor, perm);

  pack_all<<<112, 256, 0, stream>>>(Wv, Ws, Wa, Wo, wv_p, wsa_p, wo_p);

  gemm_mt<<<dim3(GX, 2), 128, 0, stream>>>(
      inpf, query, (const bf16x8*)wv_p, (const bf16x8*)wsa_p,
      bv, bs, ba, value, params);

  sampler<<<1664, 512, 0, stream>>>(refp, params, value,
                                    (const bf16x8*)wo_p, bo, perm, out);
}